// Round 6
// baseline (5218.180 us; speedup 1.0000x reference)
//
#include <hip/hip_runtime.h>
#include <stdint.h>

typedef unsigned short u16;
typedef unsigned int u32;
typedef unsigned long long u64;
typedef __attribute__((ext_vector_type(8))) short bh8;        // 8 bf16 raw (4 VGPRs)
typedef __attribute__((ext_vector_type(8))) unsigned short u16x8;
typedef __attribute__((ext_vector_type(4))) float f32x4;

#define B_ 32
#define T_ 1000
#define D_ 512
#define NG 2048   // 4*D

__device__ __forceinline__ float bf2f(u16 u) {
  union { unsigned int i; float f; } v; v.i = ((unsigned int)u) << 16; return v.f;
}
__device__ __forceinline__ u16 f2bf(float f) {
  union { float f; unsigned int i; } v; v.f = f;
  return (u16)((v.i + 0x7fffu + ((v.i >> 16) & 1u)) >> 16);   // RNE
}

// ---------------- weight transpose + f32->bf16 : dst[C][R] = src[R][C] ----------------
__global__ __launch_bounds__(256) void wtrans_k(const float* __restrict__ src,
                                                u16* __restrict__ dst, int R, int C) {
  __shared__ float tile[32][33];
  const int r0 = blockIdx.x * 32, c0 = blockIdx.y * 32;
  const int tid = threadIdx.x;
#pragma unroll
  for (int q = 0; q < 4; q++) {
    int idx = q * 256 + tid, rr = idx >> 5, cc = idx & 31;
    tile[rr][cc] = src[(size_t)(r0 + rr) * C + c0 + cc];
  }
  __syncthreads();
#pragma unroll
  for (int q = 0; q < 4; q++) {
    int idx = q * 256 + tid, cc = idx >> 5, rr = idx & 31;
    dst[(size_t)(c0 + cc) * R + r0 + rr] = f2bf(tile[rr][cc]);
  }
}

__global__ void bsum_k(const float* __restrict__ a, const float* __restrict__ b,
                       float* __restrict__ o) {
  int i = blockIdx.x * blockDim.x + threadIdx.x;
  if (i < NG) o[i] = a[i] + b[i];
}

// ---------------- x[:, 0:512] = emb[zi[b][t-1]] (0 for t==0), rows ordered (t,b) ----------------
__global__ __launch_bounds__(256) void embed_k(const int* __restrict__ zi,
                                               const float* __restrict__ emb,
                                               u16* __restrict__ x) {
  const int tid = threadIdx.x;
  const int r = blockIdx.x * 4 + (tid >> 6);        // (t*32+b), grid 8000
  const int d0 = (tid & 63) * 8;
  const int t = r >> 5, b = r & 31;
  u16x8 o;
  if (t == 0) {
#pragma unroll
    for (int i = 0; i < 8; i++) o[i] = 0;
  } else {
    const int zv = zi[b * T_ + t - 1];
    const float* s = emb + (size_t)zv * D_ + d0;
#pragma unroll
    for (int i = 0; i < 8; i++) o[i] = f2bf(s[i]);
  }
  *(u16x8*)(x + (size_t)r * 1024 + d0) = o;
}

// ---------------- x[:, 512:1024] = c[b][d][t] transposed (LDS tile) ----------------
__global__ __launch_bounds__(256) void ctrans_k(const float* __restrict__ c,
                                                u16* __restrict__ x) {
  __shared__ float tile[32][65];
  const int b = blockIdx.z, d0 = blockIdx.y * 32, t0 = blockIdx.x * 64;
  const int tid = threadIdx.x;
  const int dd = tid >> 3, tt0 = (tid & 7) * 8;
  const float* src = c + ((size_t)b * D_ + d0 + dd) * T_ + t0 + tt0;
#pragma unroll
  for (int i = 0; i < 8; i++) {
    int tt = tt0 + i;
    tile[dd][tt] = (t0 + tt < T_) ? src[i] : 0.f;
  }
  __syncthreads();
  const int tt = tid & 63, dq = tid >> 6;
  if (t0 + tt < T_) {
    u16x8 o;
#pragma unroll
    for (int i = 0; i < 8; i++) o[i] = f2bf(tile[dq * 8 + i][tt]);
    *(u16x8*)(x + ((size_t)(t0 + tt) * 32 + b) * 1024 + 512 + d0 + dq * 8) = o;
  }
}

// ---------------- bf16 MFMA GEMM: C[M,N] = act(A[M,K] @ Bt[N,K]^T + bias) ----------------
template <bool RELU, bool SCATTER>
__global__ __launch_bounds__(256, 2) void gemm_k(const u16* __restrict__ A,
                                                 const u16* __restrict__ Bt,
                                                 const float* __restrict__ bias,
                                                 void* __restrict__ Cout,
                                                 int M, int N, int K) {
  __shared__ u16 Al[128 * 40];
  __shared__ u16 Bl[128 * 40];
  const int tid = threadIdx.x;
  const int w = tid >> 6, l = tid & 63;
  const int row0 = blockIdx.x * 128, col0 = blockIdx.y * 128;
  const int wr = (w >> 1) * 64, wc = (w & 1) * 64;
  f32x4 acc[4][4];
  const f32x4 zero = {0.f, 0.f, 0.f, 0.f};
#pragma unroll
  for (int i = 0; i < 4; i++)
#pragma unroll
    for (int j = 0; j < 4; j++) acc[i][j] = zero;

  const int sm = tid >> 2;
  const int sk = (tid & 3) * 8;
  const u16* Ap = A + (size_t)(row0 + sm) * K + sk;
  const u16* Bp = Bt + (size_t)(col0 + sm) * K + sk;
  const size_t half = (size_t)64 * K;
  const int ldo = sm * 40 + sk;
  const int lr = l & 15, lk = (l >> 4) * 8;
  const int KT = K >> 5;

  bh8 a0 = *(const bh8*)Ap, a1 = *(const bh8*)(Ap + half);
  bh8 b0 = *(const bh8*)Bp, b1 = *(const bh8*)(Bp + half);

  for (int kt = 0; kt < KT; kt++) {
    const int kn = (kt + 1 < KT) ? (kt + 1) * 32 : 0;
    bh8 na0 = *(const bh8*)(Ap + kn), na1 = *(const bh8*)(Ap + half + kn);
    bh8 nb0 = *(const bh8*)(Bp + kn), nb1 = *(const bh8*)(Bp + half + kn);
    *(bh8*)(Al + ldo) = a0;
    *(bh8*)(Al + ldo + 64 * 40) = a1;
    *(bh8*)(Bl + ldo) = b0;
    *(bh8*)(Bl + ldo + 64 * 40) = b1;
    __syncthreads();
    bh8 af[4], bfr[4];
#pragma unroll
    for (int i = 0; i < 4; i++) af[i] = *(const bh8*)(Al + (wr + i * 16 + lr) * 40 + lk);
#pragma unroll
    for (int j = 0; j < 4; j++) bfr[j] = *(const bh8*)(Bl + (wc + j * 16 + lr) * 40 + lk);
#pragma unroll
    for (int i = 0; i < 4; i++)
#pragma unroll
      for (int j = 0; j < 4; j++)
        acc[i][j] = __builtin_amdgcn_mfma_f32_16x16x32_bf16(af[i], bfr[j], acc[i][j], 0, 0, 0);
    __syncthreads();
    a0 = na0; a1 = na1; b0 = nb0; b1 = nb1;
  }

  const int lrow = (l >> 4) * 4;
#pragma unroll
  for (int j = 0; j < 4; j++) {
    const int n = col0 + wc + j * 16 + lr;
    const float bv = bias[n];
#pragma unroll
    for (int i = 0; i < 4; i++) {
      const int r = row0 + wr + i * 16 + lrow;
      if (SCATTER) {  // out[b][n][t], r = b*T_+t
        const int bb = r / T_;
        const int t = r - bb * T_;
        f32x4 o;
#pragma unroll
        for (int e = 0; e < 4; e++) o[e] = acc[i][j][e] + bv;
        *(f32x4*)((float*)Cout + ((size_t)bb * N + n) * T_ + t) = o;
      } else {
#pragma unroll
        for (int e = 0; e < 4; e++) {
          float v = acc[i][j][e] + bv;
          if (RELU) v = v > 0.f ? v : 0.f;
          ((u16*)Cout)[(size_t)(r + e) * N + n] = f2bf(v);
        }
      }
    }
  }
}

// ---------------- LSTM scan v6: single-barrier step, compute wave + pure poll waves ----------------
// 8 groups x 4 batches (group = XCD under round-robin); 32 wgs/group, wg owns 16 h-dims.
// Wave 0: 64 MFMAs (4 gate tiles; lane d holds i,f,g,o for all 4 batches) + pointwise +
//   tagged sc0 payload stores (+agent-scope shadow, fire-and-forget). No vmcnt on its path.
// Waves 1-3: poll 2048 tagged dwords (6 dwordx2 pairs/lane, predicated re-poll), stage
//   MFMA A-frags into the other hstage buffer. One raw lgkm-only barrier per step.
__global__ __launch_bounds__(256, 1) void scan_k(const u16* __restrict__ xg,   // [T*B][2048] rows (t,b)
                                                 const u16* __restrict__ Whht, // [2048][512]
                                                 u16* __restrict__ hs,         // [B][T][512]
                                                 u32* hbuf) {                  // fast[2][8][4][512] + shadow
  __shared__ u16 hstage[2][16 * 512];     // [buf][frag kk][lane*8]; rows 4-15 stay zero
  const int tid = threadIdx.x;
  const int wgid = blockIdx.x;
  const int grp = wgid & 7;               // XCD id under round-robin dispatch
  const int wgin = wgid >> 3;             // 0..31 within group
  const int D0 = wgin * 16;
  const int w = tid >> 6, l = tid & 63;
  const int lr = l & 15, lc = l >> 4;

  u32* fb = hbuf;                         // fast: [2][8][4][512] u32 = 128 KB
  u32* sb = hbuf + 32768;                 // shadow (agent-scope), same layout

  // zero both hstage buffers (rows >=4 of each frag never rewritten)
  for (int i = tid; i < 2 * 16 * 256; i += 256) ((u32*)hstage)[i] = 0u;

  // wave 0: loop-invariant B fragments, 4 gate tiles x K=512 (256 VGPRs)
  bh8 bfr[4][16];
  if (w == 0) {
#pragma unroll
    for (int g = 0; g < 4; g++) {
      const u16* wp = Whht + (size_t)(g * 512 + D0 + lr) * 512 + lc * 8;
#pragma unroll
      for (int kk = 0; kk < 16; kk++) bfr[g][kk] = *(const bh8*)(wp + kk * 32);
    }
  }
  float cc4[4] = {0.f, 0.f, 0.f, 0.f};
  u16 xh[4][4];                           // [batch][gate], lane l<16 owns dim D0+l
  if (w == 0 && l < 16) {
#pragma unroll
    for (int b = 0; b < 4; b++)
#pragma unroll
      for (int g = 0; g < 4; g++)
        xh[b][g] = xg[(size_t)(grp * 4 + b) * NG + g * 512 + D0 + l];
  }
  const int ridx = (w - 1) * 64 + l;      // 0..191 for waves 1-3
  bool slowmode = false;
  __syncthreads();

  for (int t = 0; t < T_; t++) {
    const int buf = t & 1;
    if (w == 0) {
      // ---- gates = h_{t-1} @ Whh : 4 N-tiles (one per gate), K=512 ----
      f32x4 ag0 = {0.f, 0.f, 0.f, 0.f}, ag1 = ag0, ag2 = ag0, ag3 = ag0;
#pragma unroll
      for (int kk = 0; kk < 16; kk++) {
        bh8 af = *(const bh8*)(&hstage[buf][kk * 512 + l * 8]);
        ag0 = __builtin_amdgcn_mfma_f32_16x16x32_bf16(af, bfr[0][kk], ag0, 0, 0, 0);
        ag1 = __builtin_amdgcn_mfma_f32_16x16x32_bf16(af, bfr[1][kk], ag1, 0, 0, 0);
        ag2 = __builtin_amdgcn_mfma_f32_16x16x32_bf16(af, bfr[2][kk], ag2, 0, 0, 0);
        ag3 = __builtin_amdgcn_mfma_f32_16x16x32_bf16(af, bfr[3][kk], ag3, 0, 0, 0);
      }
      if (l < 16) {
        // ---- pointwise: lane l = dim D0+l, acc element e = batch ----
        u32 pk[4];
#pragma unroll
        for (int b = 0; b < 4; b++) {
          const float gi = ag0[b] + bf2f(xh[b][0]);
          const float gf = ag1[b] + bf2f(xh[b][1]);
          const float gg = ag2[b] + bf2f(xh[b][2]);
          const float go = ag3[b] + bf2f(xh[b][3]);
          const float si = 1.f / (1.f + __expf(-gi));
          const float sf = 1.f / (1.f + __expf(-gf));
          const float tg = 1.f - 2.f / (__expf(2.f * gg) + 1.f);
          const float so = 1.f / (1.f + __expf(-go));
          cc4[b] = sf * cc4[b] + si * tg;
          const float hv = so * (1.f - 2.f / (__expf(2.f * cc4[b]) + 1.f));
          pk[b] = (u32)f2bf(hv);
        }
        if (t + 1 < T_) {
          const u32 tag = (u32)(t + 1) << 16;
#pragma unroll
          for (int b = 0; b < 4; b++) {   // fast publish first (inter-wg critical path)
            const size_t idx = ((size_t)(buf * 8 + grp) * 4 + b) * 512 + D0 + l;
            asm volatile("global_store_dword %0, %1, off sc0"
                         :: "v"((u64)(uintptr_t)(fb + idx)), "v"(tag | pk[b]) : "memory");
          }
#pragma unroll
          for (int b = 0; b < 4; b++) {   // shadow publish (fire-and-forget, LLC)
            const size_t idx = ((size_t)(buf * 8 + grp) * 4 + b) * 512 + D0 + l;
            (void)__hip_atomic_exchange(sb + idx, tag | pk[b], __ATOMIC_RELAXED,
                                        __HIP_MEMORY_SCOPE_AGENT);
          }
        }
#pragma unroll
        for (int b = 0; b < 4; b++)
          hs[((size_t)(grp * 4 + b) * T_ + t) * 512 + D0 + l] = (u16)pk[b];
        if (t + 1 < T_) {
#pragma unroll
          for (int b = 0; b < 4; b++)
#pragma unroll
            for (int g = 0; g < 4; g++)
              xh[b][g] = xg[((size_t)(t + 1) * 32 + grp * 4 + b) * NG + g * 512 + D0 + l];
        }
      }
    } else if (t + 1 < T_) {
      // ---- waves 1-3: poll 6 tagged pairs/lane, stage A-frags into hstage[buf^1] ----
      const u32 tag = (u32)(t + 1);
      const size_t slot = (size_t)(buf * 8 + grp) * 2048;
      u64 q0 = 0, q1 = 0, q2 = 0, q3 = 0, q4 = 0, q5 = 0;
      bool vd[6], nd[6];
      size_t off[6];
#pragma unroll
      for (int it = 0; it < 6; it++) {
        const int p = ridx + 192 * it;
        vd[it] = (p < 1024);
        nd[it] = vd[it];
        const int b = p >> 8, k0 = (p & 255) * 2;
        off[it] = slot + (size_t)b * 512 + k0;
      }
      if (!slowmode) {
        for (int r = 0; r < 1024; r++) {
          if (nd[0]) asm volatile("global_load_dwordx2 %0, %1, off sc0" : "=v"(q0) : "v"((u64)(uintptr_t)(fb + off[0])));
          if (nd[1]) asm volatile("global_load_dwordx2 %0, %1, off sc0" : "=v"(q1) : "v"((u64)(uintptr_t)(fb + off[1])));
          if (nd[2]) asm volatile("global_load_dwordx2 %0, %1, off sc0" : "=v"(q2) : "v"((u64)(uintptr_t)(fb + off[2])));
          if (nd[3]) asm volatile("global_load_dwordx2 %0, %1, off sc0" : "=v"(q3) : "v"((u64)(uintptr_t)(fb + off[3])));
          if (nd[4]) asm volatile("global_load_dwordx2 %0, %1, off sc0" : "=v"(q4) : "v"((u64)(uintptr_t)(fb + off[4])));
          if (nd[5]) asm volatile("global_load_dwordx2 %0, %1, off sc0" : "=v"(q5) : "v"((u64)(uintptr_t)(fb + off[5])));
          asm volatile("s_waitcnt vmcnt(0)"
                       : "+v"(q0), "+v"(q1), "+v"(q2), "+v"(q3), "+v"(q4), "+v"(q5));
          __builtin_amdgcn_sched_barrier(0);
          bool any = false;
          if (nd[0]) { if (((u32)q0 >> 16) == tag && ((u32)(q0 >> 32) >> 16) == tag) nd[0] = false; else any = true; }
          if (nd[1]) { if (((u32)q1 >> 16) == tag && ((u32)(q1 >> 32) >> 16) == tag) nd[1] = false; else any = true; }
          if (nd[2]) { if (((u32)q2 >> 16) == tag && ((u32)(q2 >> 32) >> 16) == tag) nd[2] = false; else any = true; }
          if (nd[3]) { if (((u32)q3 >> 16) == tag && ((u32)(q3 >> 32) >> 16) == tag) nd[3] = false; else any = true; }
          if (nd[4]) { if (((u32)q4 >> 16) == tag && ((u32)(q4 >> 32) >> 16) == tag) nd[4] = false; else any = true; }
          if (nd[5]) { if (((u32)q5 >> 16) == tag && ((u32)(q5 >> 32) >> 16) == tag) nd[5] = false; else any = true; }
          if (!__ballot(any)) break;
        }
        if (__ballot(nd[0] | nd[1] | nd[2] | nd[3] | nd[4] | nd[5])) slowmode = true;
      }
      if (slowmode) {                     // placement-independent fallback at LLC
        for (;;) {
          bool any = false;
#pragma unroll
          for (int it = 0; it < 6; it++) {
            if (!nd[it]) continue;
            u64 qv = __hip_atomic_load((const u64*)(sb + off[it]), __ATOMIC_RELAXED,
                                       __HIP_MEMORY_SCOPE_AGENT);
            if (((u32)qv >> 16) == tag && ((u32)(qv >> 32) >> 16) == tag) {
              nd[it] = false;
              if (it == 0) q0 = qv; else if (it == 1) q1 = qv; else if (it == 2) q2 = qv;
              else if (it == 3) q3 = qv; else if (it == 4) q4 = qv; else q5 = qv;
            } else any = true;
          }
          if (!__ballot(any)) break;
        }
      }
      // stage: pair p -> frag (k0>>5), row b, u32 at even k0
      const int dbase = (buf ^ 1) * 8192;
#pragma unroll
      for (int it = 0; it < 6; it++) {
        if (!vd[it]) continue;
        const int p = ridx + 192 * it;
        const int b = p >> 8, k0 = (p & 255) * 2;
        u64 qv = (it == 0) ? q0 : (it == 1) ? q1 : (it == 2) ? q2
               : (it == 3) ? q3 : (it == 4) ? q4 : q5;
        const u32 word = ((u32)qv & 0xffffu) | (((u32)(qv >> 32) & 0xffffu) << 16);
        const int di = dbase + (k0 >> 5) * 512 + (((k0 >> 3) & 3) * 16 + b) * 8 + (k0 & 7);
        *(u32*)(&hstage[0][0] + di) = word;
      }
    }
    // ---- single raw barrier: LDS-only drain (global stores/loads stay in flight) ----
    asm volatile("s_waitcnt lgkmcnt(0)\n\ts_barrier" ::: "memory");
    __builtin_amdgcn_sched_barrier(0);
  }
}

extern "C" void kernel_launch(void* const* d_in, const int* in_sizes, int n_in,
                              void* d_out, int out_size, void* d_ws, size_t ws_size,
                              hipStream_t stream) {
  const int*   zi    = (const int*)d_in[0];
  const float* c     = (const float*)d_in[1];
  const float* emb   = (const float*)d_in[2];
  const float* W1    = (const float*)d_in[3];
  const float* b1    = (const float*)d_in[4];
  const float* W2    = (const float*)d_in[5];
  const float* b2    = (const float*)d_in[6];
  const float* W_ih  = (const float*)d_in[7];
  const float* b_ih  = (const float*)d_in[8];
  const float* W_hh  = (const float*)d_in[9];
  const float* b_hh  = (const float*)d_in[10];
  const float* W_out = (const float*)d_in[11];
  const float* b_out = (const float*)d_in[12];
  float* out = (float*)d_out;
  char* ws = (char*)d_ws;

  const size_t x_off   = 0;
  const size_t xg_off  = 65536000;
  const size_t pre_off = 32768000;
  const size_t w_off   = xg_off + 131072000;
  u16* xb    = (u16*)(ws + x_off);
  u16* hsb   = (u16*)(ws + x_off);
  u16* preb  = (u16*)(ws + pre_off);
  u16* xgb   = (u16*)(ws + xg_off);
  u16* h1b   = (u16*)(ws + xg_off);
  u16* W1t   = (u16*)(ws + w_off);           // [512][1024]
  u16* W2t   = W1t + 512 * 1024;             // [512][512]
  u16* Wiht  = W2t + 512 * 512;              // [2048][512]
  u16* Whht  = Wiht + 2048 * 512;            // [2048][512]
  u16* Woutt = Whht + 2048 * 512;            // [512][512]
  float* bsum = (float*)(Woutt + 512 * 512);
  u32* hbuf  = (u32*)(bsum + NG);            // fast 128KB + shadow 128KB

  hipMemsetAsync(hbuf, 0, 2 * 2 * 8 * 4 * 512 * sizeof(u32), stream);

  wtrans_k<<<dim3(32, 16), 256, 0, stream>>>(W1, W1t, 1024, 512);
  wtrans_k<<<dim3(16, 16), 256, 0, stream>>>(W2, W2t, 512, 512);
  wtrans_k<<<dim3(16, 64), 256, 0, stream>>>(W_ih, Wiht, 512, 2048);
  wtrans_k<<<dim3(16, 64), 256, 0, stream>>>(W_hh, Whht, 512, 2048);
  wtrans_k<<<dim3(16, 16), 256, 0, stream>>>(W_out, Woutt, 512, 512);
  bsum_k<<<8, 256, 0, stream>>>(b_ih, b_hh, bsum);
  embed_k<<<8000, 256, 0, stream>>>(zi, emb, xb);
  ctrans_k<<<dim3(16, 16, 32), 256, 0, stream>>>(c, xb);

  gemm_k<true,  false><<<dim3(250, 4),  256, 0, stream>>>(xb,   W1t,   b1,    h1b,  32000, 512,  1024);
  gemm_k<false, false><<<dim3(250, 4),  256, 0, stream>>>(h1b,  W2t,   b2,    preb, 32000, 512,  512);
  gemm_k<false, false><<<dim3(250, 16), 256, 0, stream>>>(preb, Wiht,  bsum,  xgb,  32000, 2048, 512);
  scan_k<<<256, 256, 0, stream>>>(xgb, Whht, hsb, hbuf);
  gemm_k<false, true ><<<dim3(250, 4),  256, 0, stream>>>(hsb,  Woutt, b_out, out,  32000, 512,  512);
}

// Round 7
// 3191.808 us; speedup vs baseline: 1.6349x; 1.6349x over previous
//
#include <hip/hip_runtime.h>
#include <stdint.h>

typedef unsigned short u16;
typedef unsigned int u32;
typedef unsigned long long u64;
typedef __attribute__((ext_vector_type(8))) short bh8;        // 8 bf16 raw (4 VGPRs)
typedef __attribute__((ext_vector_type(8))) unsigned short u16x8;
typedef __attribute__((ext_vector_type(4))) float f32x4;

#define B_ 32
#define T_ 1000
#define D_ 512
#define NG 2048   // 4*D

__device__ __forceinline__ float bf2f(u16 u) {
  union { unsigned int i; float f; } v; v.i = ((unsigned int)u) << 16; return v.f;
}
__device__ __forceinline__ u16 f2bf(float f) {
  union { float f; unsigned int i; } v; v.f = f;
  return (u16)((v.i + 0x7fffu + ((v.i >> 16) & 1u)) >> 16);   // RNE
}

// ---------------- weight transpose + f32->bf16 : dst[C][R] = src[R][C] ----------------
__global__ __launch_bounds__(256) void wtrans_k(const float* __restrict__ src,
                                                u16* __restrict__ dst, int R, int C) {
  __shared__ float tile[32][33];
  const int r0 = blockIdx.x * 32, c0 = blockIdx.y * 32;
  const int tid = threadIdx.x;
#pragma unroll
  for (int q = 0; q < 4; q++) {
    int idx = q * 256 + tid, rr = idx >> 5, cc = idx & 31;
    tile[rr][cc] = src[(size_t)(r0 + rr) * C + c0 + cc];
  }
  __syncthreads();
#pragma unroll
  for (int q = 0; q < 4; q++) {
    int idx = q * 256 + tid, cc = idx >> 5, rr = idx & 31;
    dst[(size_t)(c0 + cc) * R + r0 + rr] = f2bf(tile[rr][cc]);
  }
}

__global__ void bsum_k(const float* __restrict__ a, const float* __restrict__ b,
                       float* __restrict__ o) {
  int i = blockIdx.x * blockDim.x + threadIdx.x;
  if (i < NG) o[i] = a[i] + b[i];
}

// ---------------- x[:, 0:512] = emb[zi[b][t-1]] (0 for t==0), rows ordered (t,b) ----------------
__global__ __launch_bounds__(256) void embed_k(const int* __restrict__ zi,
                                               const float* __restrict__ emb,
                                               u16* __restrict__ x) {
  const int tid = threadIdx.x;
  const int r = blockIdx.x * 4 + (tid >> 6);        // (t*32+b), grid 8000
  const int d0 = (tid & 63) * 8;
  const int t = r >> 5, b = r & 31;
  u16x8 o;
  if (t == 0) {
#pragma unroll
    for (int i = 0; i < 8; i++) o[i] = 0;
  } else {
    const int zv = zi[b * T_ + t - 1];
    const float* s = emb + (size_t)zv * D_ + d0;
#pragma unroll
    for (int i = 0; i < 8; i++) o[i] = f2bf(s[i]);
  }
  *(u16x8*)(x + (size_t)r * 1024 + d0) = o;
}

// ---------------- x[:, 512:1024] = c[b][d][t] transposed (LDS tile) ----------------
__global__ __launch_bounds__(256) void ctrans_k(const float* __restrict__ c,
                                                u16* __restrict__ x) {
  __shared__ float tile[32][65];
  const int b = blockIdx.z, d0 = blockIdx.y * 32, t0 = blockIdx.x * 64;
  const int tid = threadIdx.x;
  const int dd = tid >> 3, tt0 = (tid & 7) * 8;
  const float* src = c + ((size_t)b * D_ + d0 + dd) * T_ + t0 + tt0;
#pragma unroll
  for (int i = 0; i < 8; i++) {
    int tt = tt0 + i;
    tile[dd][tt] = (t0 + tt < T_) ? src[i] : 0.f;
  }
  __syncthreads();
  const int tt = tid & 63, dq = tid >> 6;
  if (t0 + tt < T_) {
    u16x8 o;
#pragma unroll
    for (int i = 0; i < 8; i++) o[i] = f2bf(tile[dq * 8 + i][tt]);
    *(u16x8*)(x + ((size_t)(t0 + tt) * 32 + b) * 1024 + 512 + d0 + dq * 8) = o;
  }
}

// ---------------- bf16 MFMA GEMM: C[M,N] = act(A[M,K] @ Bt[N,K]^T + bias) ----------------
template <bool RELU, bool SCATTER>
__global__ __launch_bounds__(256, 2) void gemm_k(const u16* __restrict__ A,
                                                 const u16* __restrict__ Bt,
                                                 const float* __restrict__ bias,
                                                 void* __restrict__ Cout,
                                                 int M, int N, int K) {
  __shared__ u16 Al[128 * 40];
  __shared__ u16 Bl[128 * 40];
  const int tid = threadIdx.x;
  const int w = tid >> 6, l = tid & 63;
  const int row0 = blockIdx.x * 128, col0 = blockIdx.y * 128;
  const int wr = (w >> 1) * 64, wc = (w & 1) * 64;
  f32x4 acc[4][4];
  const f32x4 zero = {0.f, 0.f, 0.f, 0.f};
#pragma unroll
  for (int i = 0; i < 4; i++)
#pragma unroll
    for (int j = 0; j < 4; j++) acc[i][j] = zero;

  const int sm = tid >> 2;
  const int sk = (tid & 3) * 8;
  const u16* Ap = A + (size_t)(row0 + sm) * K + sk;
  const u16* Bp = Bt + (size_t)(col0 + sm) * K + sk;
  const size_t half = (size_t)64 * K;
  const int ldo = sm * 40 + sk;
  const int lr = l & 15, lk = (l >> 4) * 8;
  const int KT = K >> 5;

  bh8 a0 = *(const bh8*)Ap, a1 = *(const bh8*)(Ap + half);
  bh8 b0 = *(const bh8*)Bp, b1 = *(const bh8*)(Bp + half);

  for (int kt = 0; kt < KT; kt++) {
    const int kn = (kt + 1 < KT) ? (kt + 1) * 32 : 0;
    bh8 na0 = *(const bh8*)(Ap + kn), na1 = *(const bh8*)(Ap + half + kn);
    bh8 nb0 = *(const bh8*)(Bp + kn), nb1 = *(const bh8*)(Bp + half + kn);
    *(bh8*)(Al + ldo) = a0;
    *(bh8*)(Al + ldo + 64 * 40) = a1;
    *(bh8*)(Bl + ldo) = b0;
    *(bh8*)(Bl + ldo + 64 * 40) = b1;
    __syncthreads();
    bh8 af[4], bfr[4];
#pragma unroll
    for (int i = 0; i < 4; i++) af[i] = *(const bh8*)(Al + (wr + i * 16 + lr) * 40 + lk);
#pragma unroll
    for (int j = 0; j < 4; j++) bfr[j] = *(const bh8*)(Bl + (wc + j * 16 + lr) * 40 + lk);
#pragma unroll
    for (int i = 0; i < 4; i++)
#pragma unroll
      for (int j = 0; j < 4; j++)
        acc[i][j] = __builtin_amdgcn_mfma_f32_16x16x32_bf16(af[i], bfr[j], acc[i][j], 0, 0, 0);
    __syncthreads();
    a0 = na0; a1 = na1; b0 = nb0; b1 = nb1;
  }

  const int lrow = (l >> 4) * 4;
#pragma unroll
  for (int j = 0; j < 4; j++) {
    const int n = col0 + wc + j * 16 + lr;
    const float bv = bias[n];
#pragma unroll
    for (int i = 0; i < 4; i++) {
      const int r = row0 + wr + i * 16 + lrow;
      if (SCATTER) {  // out[b][n][t], r = b*T_+t
        const int bb = r / T_;
        const int t = r - bb * T_;
        f32x4 o;
#pragma unroll
        for (int e = 0; e < 4; e++) o[e] = acc[i][j][e] + bv;
        *(f32x4*)((float*)Cout + ((size_t)bb * N + n) * T_ + t) = o;
      } else {
#pragma unroll
        for (int e = 0; e < 4; e++) {
          float v = acc[i][j][e] + bv;
          if (RELU) v = v > 0.f ? v : 0.f;
          ((u16*)Cout)[(size_t)(r + e) * N + n] = f2bf(v);
        }
      }
    }
  }
}

// ---- sc0 (SE-scope: bypass L1, hit local L2) / sc1 (agent: coherence point) poll ----
__device__ __forceinline__ void poll8(const u32* p, u64 q[8], bool slow) {
  const u64 a = (u64)(uintptr_t)p;
  if (!slow) {
    asm volatile(
        "global_load_dwordx2 %0, %8, off sc0\n\t"
        "global_load_dwordx2 %1, %8, off offset:256 sc0\n\t"
        "global_load_dwordx2 %2, %8, off offset:512 sc0\n\t"
        "global_load_dwordx2 %3, %8, off offset:768 sc0\n\t"
        "global_load_dwordx2 %4, %8, off offset:1024 sc0\n\t"
        "global_load_dwordx2 %5, %8, off offset:1280 sc0\n\t"
        "global_load_dwordx2 %6, %8, off offset:1536 sc0\n\t"
        "global_load_dwordx2 %7, %8, off offset:1792 sc0\n\t"
        "s_waitcnt vmcnt(0)"
        : "=&v"(q[0]), "=&v"(q[1]), "=&v"(q[2]), "=&v"(q[3]),
          "=&v"(q[4]), "=&v"(q[5]), "=&v"(q[6]), "=&v"(q[7])
        : "v"(a)
        : "memory");
  } else {
    asm volatile(
        "global_load_dwordx2 %0, %8, off sc1\n\t"
        "global_load_dwordx2 %1, %8, off offset:256 sc1\n\t"
        "global_load_dwordx2 %2, %8, off offset:512 sc1\n\t"
        "global_load_dwordx2 %3, %8, off offset:768 sc1\n\t"
        "global_load_dwordx2 %4, %8, off offset:1024 sc1\n\t"
        "global_load_dwordx2 %5, %8, off offset:1280 sc1\n\t"
        "global_load_dwordx2 %6, %8, off offset:1536 sc1\n\t"
        "global_load_dwordx2 %7, %8, off offset:1792 sc1\n\t"
        "s_waitcnt vmcnt(0)"
        : "=&v"(q[0]), "=&v"(q[1]), "=&v"(q[2]), "=&v"(q[3]),
          "=&v"(q[4]), "=&v"(q[5]), "=&v"(q[6]), "=&v"(q[7])
        : "v"(a)
        : "memory");
  }
}

// ---------------- LSTM scan v7: v5 structure + drain-free (lgkm-only) barriers ----------------
// 8 groups x 4 batches (group = XCD under round-robin dispatch); 32 wgs/group, wg owns 16 h-dims.
// Wave 0: 4-tile MFMA + pointwise + tagged sc0 publish (+agent shadow, fire-and-forget).
// Waves 2-3: batched sc0 tag poll -> stage MFMA A-frags. Barriers drain LDS only: no vmem
// ordering is needed anywhere (tag travels with payload; xg regs waited at first use).
__global__ __launch_bounds__(256, 1) void scan_k(const u16* __restrict__ xg,   // [T*B][2048] rows (t,b)
                                                 const u16* __restrict__ Whht, // [2048][512]
                                                 u16* __restrict__ hs,         // [B][T][512]
                                                 u32* hbuf) {                  // fast[2][8][4][512] + shadow
  __shared__ u16 hstage[16 * 512];        // 16 A-frags (K=512), rows 0-3 = batches, rest zero
  __shared__ float gl[4][68];             // [batch][gate*16 + dim]
  const int tid = threadIdx.x;
  const int wgid = blockIdx.x;
  const int grp = wgid & 7;               // XCD id under round-robin dispatch
  const int wgin = wgid >> 3;             // 0..31 within group
  const int D0 = wgin * 16;
  const int w = tid >> 6, l = tid & 63;
  const int lr = l & 15, lc = l >> 4;

  u32* fb = hbuf;                         // fast: [2][8][4][512] u32 = 128 KB
  u32* sb = hbuf + 32768;                 // slow shadow, same layout

  // loop-invariant B fragments: wave w = gate w, cols D0..D0+15 (64 VGPRs)
  bh8 bfr[16];
  {
    const u16* wp = Whht + (size_t)(w * 512 + D0 + lr) * 512 + lc * 8;
#pragma unroll
    for (int kk = 0; kk < 16; kk++) bfr[kk] = *(const bh8*)(wp + kk * 32);
  }

  // h_{-1} = 0 (rows >=4 of every frag stay zero forever)
  for (int i = tid; i < 16 * 256; i += 256) ((u32*)hstage)[i] = 0u;

  // writer mapping (wave 0): lane -> (batch b, dim d)
  const int pb = l >> 4, pd = l & 15;
  const int gbat = grp * 4 + pb;
  float ccv = 0.f;
  u16 xh[4];
  if (w == 0) {
    const u16* xp = xg + (size_t)gbat * NG + D0 + pd;        // t = 0 rows
#pragma unroll
    for (int g = 0; g < 4; g++) xh[g] = xp[g * 512];
  }
  // reader mapping (waves 2,3): lane -> (batch rb, dim-pair column l5)
  const int rb = (w - 2) * 2 + (l >> 5);
  const int l5 = l & 31;
  bool slowmode = false;
  __syncthreads();

  for (int t = 0; t < T_; t++) {
    // ---- gates = h_{t-1} @ Whh : one M=4,N=16 tile per wave, K=512 ----
    f32x4 e0 = {0.f, 0.f, 0.f, 0.f}, e1 = e0;
#pragma unroll
    for (int kk = 0; kk < 16; kk += 2) {
      bh8 af0 = *(const bh8*)(hstage + (kk + 0) * 512 + l * 8);
      bh8 af1 = *(const bh8*)(hstage + (kk + 1) * 512 + l * 8);
      e0 = __builtin_amdgcn_mfma_f32_16x16x32_bf16(af0, bfr[kk + 0], e0, 0, 0, 0);
      e1 = __builtin_amdgcn_mfma_f32_16x16x32_bf16(af1, bfr[kk + 1], e1, 0, 0, 0);
    }
    const f32x4 acc = e0 + e1;
    if (lc == 0) {                        // rows 0-3 = batches
#pragma unroll
      for (int e = 0; e < 4; e++) gl[e][w * 16 + lr] = acc[e];
    }
    // B1: LDS-only drain barrier (no vmem on anyone's required path)
    asm volatile("s_waitcnt lgkmcnt(0)\n\ts_barrier" ::: "memory");
    __builtin_amdgcn_sched_barrier(0);

    if (w == 0) {
      // ---- pointwise: one h-value per lane (batch pb, dim D0+pd) ----
      const float gi = gl[pb][ 0 + pd] + bf2f(xh[0]);
      const float gf = gl[pb][16 + pd] + bf2f(xh[1]);
      const float gg = gl[pb][32 + pd] + bf2f(xh[2]);
      const float go = gl[pb][48 + pd] + bf2f(xh[3]);
      const float si = 1.f / (1.f + __expf(-gi));
      const float sf = 1.f / (1.f + __expf(-gf));
      const float tg = 1.f - 2.f / (__expf(2.f * gg) + 1.f);
      const float so = 1.f / (1.f + __expf(-go));
      ccv = sf * ccv + si * tg;
      const float hv = so * (1.f - 2.f / (__expf(2.f * ccv) + 1.f));
      const u16 hb = f2bf(hv);
      if (t + 1 < T_) {
        const u32 tagged = ((u32)(t + 1) << 16) | (u32)hb;
        const size_t idx = ((size_t)((t & 1) * 8 + grp) * 4 + pb) * 512 + D0 + pd;
        asm volatile("global_store_dword %0, %1, off sc0"
                     :: "v"((u64)(uintptr_t)(fb + idx)), "v"(tagged) : "memory");
        (void)__hip_atomic_exchange(sb + idx, tagged, __ATOMIC_RELAXED,
                                    __HIP_MEMORY_SCOPE_AGENT);
      }
      hs[((size_t)gbat * T_ + t) * 512 + D0 + pd] = hb;
      if (t + 1 < T_) {
        const u16* xp = xg + ((size_t)(t + 1) * 32 + gbat) * NG + D0 + pd;
#pragma unroll
        for (int g = 0; g < 4; g++) xh[g] = xp[g * 512];
      }
    } else if (w >= 2 && t + 1 < T_) {
      // ---- readers: poll 8 dim-pairs (batch rb, dims 2*l5+64s, +1), stage A-frags ----
      const u32 tag = (u32)(t + 1);
      const size_t base = ((size_t)((t & 1) * 8 + grp) * 4 + rb) * 512 + 2 * l5;
      u64 q[8];
      int rounds = 0;
      for (;;) {
        poll8(fb + base, q, false);
        if (slowmode) poll8(sb + base, q, true);
        u32 bad = 0;
#pragma unroll
        for (int s = 0; s < 8; s++) {
          bad |= ((u32)q[s] >> 16) ^ tag;
          bad |= ((u32)(q[s] >> 32) >> 16) ^ tag;
        }
        if (!__ballot(bad != 0u)) break;
        if (++rounds > 256) slowmode = true;
      }
#pragma unroll
      for (int s = 0; s < 8; s++) {
        const int k = 2 * l5 + 64 * s;
        const u32 wv = ((u32)q[s] & 0xffffu) | ((u32)(q[s] >> 32) << 16);
        *(u32*)(hstage + (k >> 5) * 512 + (rb + ((k >> 3) & 3) * 16) * 8 + (k & 7)) = wv;
      }
    }
    // B2: LDS-only drain barrier — hstage(t) ready; globals stay in flight
    asm volatile("s_waitcnt lgkmcnt(0)\n\ts_barrier" ::: "memory");
    __builtin_amdgcn_sched_barrier(0);
  }
}

extern "C" void kernel_launch(void* const* d_in, const int* in_sizes, int n_in,
                              void* d_out, int out_size, void* d_ws, size_t ws_size,
                              hipStream_t stream) {
  const int*   zi    = (const int*)d_in[0];
  const float* c     = (const float*)d_in[1];
  const float* emb   = (const float*)d_in[2];
  const float* W1    = (const float*)d_in[3];
  const float* b1    = (const float*)d_in[4];
  const float* W2    = (const float*)d_in[5];
  const float* b2    = (const float*)d_in[6];
  const float* W_ih  = (const float*)d_in[7];
  const float* b_ih  = (const float*)d_in[8];
  const float* W_hh  = (const float*)d_in[9];
  const float* b_hh  = (const float*)d_in[10];
  const float* W_out = (const float*)d_in[11];
  const float* b_out = (const float*)d_in[12];
  float* out = (float*)d_out;
  char* ws = (char*)d_ws;

  const size_t x_off   = 0;
  const size_t xg_off  = 65536000;
  const size_t pre_off = 32768000;
  const size_t w_off   = xg_off + 131072000;
  u16* xb    = (u16*)(ws + x_off);
  u16* hsb   = (u16*)(ws + x_off);
  u16* preb  = (u16*)(ws + pre_off);
  u16* xgb   = (u16*)(ws + xg_off);
  u16* h1b   = (u16*)(ws + xg_off);
  u16* W1t   = (u16*)(ws + w_off);           // [512][1024]
  u16* W2t   = W1t + 512 * 1024;             // [512][512]
  u16* Wiht  = W2t + 512 * 512;              // [2048][512]
  u16* Whht  = Wiht + 2048 * 512;            // [2048][512]
  u16* Woutt = Whht + 2048 * 512;            // [512][512]
  float* bsum = (float*)(Woutt + 512 * 512);
  u32* hbuf  = (u32*)(bsum + NG);            // fast 128KB + shadow 128KB

  hipMemsetAsync(hbuf, 0, 2 * 2 * 8 * 4 * 512 * sizeof(u32), stream);

  wtrans_k<<<dim3(32, 16), 256, 0, stream>>>(W1, W1t, 1024, 512);
  wtrans_k<<<dim3(16, 16), 256, 0, stream>>>(W2, W2t, 512, 512);
  wtrans_k<<<dim3(16, 64), 256, 0, stream>>>(W_ih, Wiht, 512, 2048);
  wtrans_k<<<dim3(16, 64), 256, 0, stream>>>(W_hh, Whht, 512, 2048);
  wtrans_k<<<dim3(16, 16), 256, 0, stream>>>(W_out, Woutt, 512, 512);
  bsum_k<<<8, 256, 0, stream>>>(b_ih, b_hh, bsum);
  embed_k<<<8000, 256, 0, stream>>>(zi, emb, xb);
  ctrans_k<<<dim3(16, 16, 32), 256, 0, stream>>>(c, xb);

  gemm_k<true,  false><<<dim3(250, 4),  256, 0, stream>>>(xb,   W1t,   b1,    h1b,  32000, 512,  1024);
  gemm_k<false, false><<<dim3(250, 4),  256, 0, stream>>>(h1b,  W2t,   b2,    preb, 32000, 512,  512);
  gemm_k<false, false><<<dim3(250, 16), 256, 0, stream>>>(preb, Wiht,  bsum,  xgb,  32000, 2048, 512);
  scan_k<<<256, 256, 0, stream>>>(xgb, Whht, hsb, hbuf);
  gemm_k<false, true ><<<dim3(250, 4),  256, 0, stream>>>(hsb,  Woutt, b_out, out,  32000, 512,  512);
}

// Round 9
// 2969.950 us; speedup vs baseline: 1.7570x; 1.0747x over previous
//
#include <hip/hip_runtime.h>
#include <stdint.h>

typedef unsigned short u16;
typedef unsigned int u32;
typedef unsigned long long u64;
typedef __attribute__((ext_vector_type(8))) short bh8;        // 8 bf16 raw (4 VGPRs)
typedef __attribute__((ext_vector_type(8))) unsigned short u16x8;
typedef __attribute__((ext_vector_type(4))) float f32x4;
typedef __attribute__((ext_vector_type(4))) unsigned int u32x4;

#define B_ 32
#define T_ 1000
#define D_ 512
#define NG 2048   // 4*D

__device__ __forceinline__ float bf2f(u16 u) {
  union { unsigned int i; float f; } v; v.i = ((unsigned int)u) << 16; return v.f;
}
__device__ __forceinline__ u16 f2bf(float f) {
  union { float f; unsigned int i; } v; v.f = f;
  return (u16)((v.i + 0x7fffu + ((v.i >> 16) & 1u)) >> 16);   // RNE
}

// ---------------- weight transpose + f32->bf16 : dst[C][R] = src[R][C] ----------------
__global__ __launch_bounds__(256) void wtrans_k(const float* __restrict__ src,
                                                u16* __restrict__ dst, int R, int C) {
  __shared__ float tile[32][33];
  const int r0 = blockIdx.x * 32, c0 = blockIdx.y * 32;
  const int tid = threadIdx.x;
#pragma unroll
  for (int q = 0; q < 4; q++) {
    int idx = q * 256 + tid, rr = idx >> 5, cc = idx & 31;
    tile[rr][cc] = src[(size_t)(r0 + rr) * C + c0 + cc];
  }
  __syncthreads();
#pragma unroll
  for (int q = 0; q < 4; q++) {
    int idx = q * 256 + tid, cc = idx >> 5, rr = idx & 31;
    dst[(size_t)(c0 + cc) * R + r0 + rr] = f2bf(tile[rr][cc]);
  }
}

__global__ void bsum_k(const float* __restrict__ a, const float* __restrict__ b,
                       float* __restrict__ o) {
  int i = blockIdx.x * blockDim.x + threadIdx.x;
  if (i < NG) o[i] = a[i] + b[i];
}

// ---------------- x[:, 0:512] = emb[zi[b][t-1]] (0 for t==0), rows ordered (t,b) ----------------
__global__ __launch_bounds__(256) void embed_k(const int* __restrict__ zi,
                                               const float* __restrict__ emb,
                                               u16* __restrict__ x) {
  const int tid = threadIdx.x;
  const int r = blockIdx.x * 4 + (tid >> 6);        // (t*32+b), grid 8000
  const int d0 = (tid & 63) * 8;
  const int t = r >> 5, b = r & 31;
  u16x8 o;
  if (t == 0) {
#pragma unroll
    for (int i = 0; i < 8; i++) o[i] = 0;
  } else {
    const int zv = zi[b * T_ + t - 1];
    const float* s = emb + (size_t)zv * D_ + d0;
#pragma unroll
    for (int i = 0; i < 8; i++) o[i] = f2bf(s[i]);
  }
  *(u16x8*)(x + (size_t)r * 1024 + d0) = o;
}

// ---------------- x[:, 512:1024] = c[b][d][t] transposed (LDS tile) ----------------
__global__ __launch_bounds__(256) void ctrans_k(const float* __restrict__ c,
                                                u16* __restrict__ x) {
  __shared__ float tile[32][65];
  const int b = blockIdx.z, d0 = blockIdx.y * 32, t0 = blockIdx.x * 64;
  const int tid = threadIdx.x;
  const int dd = tid >> 3, tt0 = (tid & 7) * 8;
  const float* src = c + ((size_t)b * D_ + d0 + dd) * T_ + t0 + tt0;
#pragma unroll
  for (int i = 0; i < 8; i++) {
    int tt = tt0 + i;
    tile[dd][tt] = (t0 + tt < T_) ? src[i] : 0.f;
  }
  __syncthreads();
  const int tt = tid & 63, dq = tid >> 6;
  if (t0 + tt < T_) {
    u16x8 o;
#pragma unroll
    for (int i = 0; i < 8; i++) o[i] = f2bf(tile[dq * 8 + i][tt]);
    *(u16x8*)(x + ((size_t)(t0 + tt) * 32 + b) * 1024 + 512 + d0 + dq * 8) = o;
  }
}

// ---------------- bf16 MFMA GEMM: C[M,N] = act(A[M,K] @ Bt[N,K]^T + bias) ----------------
template <bool RELU, bool SCATTER>
__global__ __launch_bounds__(256, 2) void gemm_k(const u16* __restrict__ A,
                                                 const u16* __restrict__ Bt,
                                                 const float* __restrict__ bias,
                                                 void* __restrict__ Cout,
                                                 int M, int N, int K) {
  __shared__ u16 Al[128 * 40];
  __shared__ u16 Bl[128 * 40];
  const int tid = threadIdx.x;
  const int w = tid >> 6, l = tid & 63;
  const int row0 = blockIdx.x * 128, col0 = blockIdx.y * 128;
  const int wr = (w >> 1) * 64, wc = (w & 1) * 64;
  f32x4 acc[4][4];
  const f32x4 zero = {0.f, 0.f, 0.f, 0.f};
#pragma unroll
  for (int i = 0; i < 4; i++)
#pragma unroll
    for (int j = 0; j < 4; j++) acc[i][j] = zero;

  const int sm = tid >> 2;
  const int sk = (tid & 3) * 8;
  const u16* Ap = A + (size_t)(row0 + sm) * K + sk;
  const u16* Bp = Bt + (size_t)(col0 + sm) * K + sk;
  const size_t half = (size_t)64 * K;
  const int ldo = sm * 40 + sk;
  const int lr = l & 15, lk = (l >> 4) * 8;
  const int KT = K >> 5;

  bh8 a0 = *(const bh8*)Ap, a1 = *(const bh8*)(Ap + half);
  bh8 b0 = *(const bh8*)Bp, b1 = *(const bh8*)(Bp + half);

  for (int kt = 0; kt < KT; kt++) {
    const int kn = (kt + 1 < KT) ? (kt + 1) * 32 : 0;
    bh8 na0 = *(const bh8*)(Ap + kn), na1 = *(const bh8*)(Ap + half + kn);
    bh8 nb0 = *(const bh8*)(Bp + kn), nb1 = *(const bh8*)(Bp + half + kn);
    *(bh8*)(Al + ldo) = a0;
    *(bh8*)(Al + ldo + 64 * 40) = a1;
    *(bh8*)(Bl + ldo) = b0;
    *(bh8*)(Bl + ldo + 64 * 40) = b1;
    __syncthreads();
    bh8 af[4], bfr[4];
#pragma unroll
    for (int i = 0; i < 4; i++) af[i] = *(const bh8*)(Al + (wr + i * 16 + lr) * 40 + lk);
#pragma unroll
    for (int j = 0; j < 4; j++) bfr[j] = *(const bh8*)(Bl + (wc + j * 16 + lr) * 40 + lk);
#pragma unroll
    for (int i = 0; i < 4; i++)
#pragma unroll
      for (int j = 0; j < 4; j++)
        acc[i][j] = __builtin_amdgcn_mfma_f32_16x16x32_bf16(af[i], bfr[j], acc[i][j], 0, 0, 0);
    __syncthreads();
    a0 = na0; a1 = na1; b0 = nb0; b1 = nb1;
  }

  const int lrow = (l >> 4) * 4;
#pragma unroll
  for (int j = 0; j < 4; j++) {
    const int n = col0 + wc + j * 16 + lr;
    const float bv = bias[n];
#pragma unroll
    for (int i = 0; i < 4; i++) {
      const int r = row0 + wr + i * 16 + lrow;
      if (SCATTER) {  // out[b][n][t], r = b*T_+t
        const int bb = r / T_;
        const int t = r - bb * T_;
        f32x4 o;
#pragma unroll
        for (int e = 0; e < 4; e++) o[e] = acc[i][j][e] + bv;
        *(f32x4*)((float*)Cout + ((size_t)bb * N + n) * T_ + t) = o;
      } else {
#pragma unroll
        for (int e = 0; e < 4; e++) {
          float v = acc[i][j][e] + bv;
          if (RELU) v = v > 0.f ? v : 0.f;
          ((u16*)Cout)[(size_t)(r + e) * N + n] = f2bf(v);
        }
      }
    }
  }
}

// ---------------- LSTM scan v9: 16 active wgs/XCD (grid 256), early shadow publish ----------------
// 8 groups x 4 batches (group = XCD via the grid-256 round-robin validated in v5/v7).
// Active wgs: wgin = wgid>>3 < 16; wg owns 32 h-dims (128 gate cols; 4 waves x 2 tiles).
// Step: MFMA -> B1 -> [thr<128: pointwise + sc0 publish + agent-shadow publish] ->
//       all: poll 2 contig dwordx4 -> stage b128 -> [thr<128: hs, xg prefetch] -> B2.
// Shadow is published BEFORE any poll -> all-slowmode degrades to v4 pace, never deadlocks.
__global__ __launch_bounds__(256, 1) void scan_k(const u16* __restrict__ xg,   // [T*B][2048] rows (t,b)
                                                 const u16* __restrict__ Whht, // [2048][512]
                                                 u16* __restrict__ hs,         // [B][T][512]
                                                 u32* hbuf) {                  // fast[2][8][4][512] + shadow
  __shared__ u16 hstage[16 * 552];        // frag kk at kk*552; octet lc at +lc*136; row r at +r*8
  __shared__ float gl[4 * 132];           // [batch][gate*32 + dim]
  const int tid = threadIdx.x;
  const int wgid = blockIdx.x;
  const int grp = wgid & 7;               // XCD id under round-robin dispatch
  const int wgin = wgid >> 3;             // 0..31; only 0..15 active
  if (wgin >= 16) return;                 // idle wgs exit before any barrier
  const int D0 = wgin * 32;
  const int w = tid >> 6, l = tid & 63;
  const int lr = l & 15, lc = l >> 4;
  const int aoff = lc * 136 + lr * 8;     // A-frag u16 offset within a frag

  u32* fb = hbuf;                         // fast: [2][8][4][512] u32 = 128 KB
  u32* sb = hbuf + 32768;                 // shadow (agent-scope), same layout

  // loop-invariant B fragments: wave w = gate w, tiles j=0,1 -> dims D0+16j..+15 (128 VGPRs)
  bh8 bfr[2][16];
#pragma unroll
  for (int j = 0; j < 2; j++) {
    const int c = w * 512 + D0 + j * 16 + lr;      // gate*512 + global dim
    const u16* wp = Whht + (size_t)c * 512 + lc * 8;
#pragma unroll
    for (int kk = 0; kk < 16; kk++) bfr[j][kk] = *(const bh8*)(wp + kk * 32);
  }

  // zero hstage (rows 4-15 of every frag stay zero forever)
  for (int i = tid; i < 16 * 552 / 2; i += 256) ((u32*)hstage)[i] = 0u;

  // writer mapping (threads 0-127): (batch pb, dim D0+pd)
  const int pb = tid >> 5, pd = tid & 31;
  const int gbat = grp * 4 + pb;
  const int gdim = D0 + pd;
  float ccv = 0.f;
  u16 xh[4];
  if (tid < 128) {
    const u16* xp = xg + (size_t)gbat * NG + gdim;             // t = 0 rows
#pragma unroll
    for (int g = 0; g < 4; g++) xh[g] = xp[g * 512];
  }
  // reader mapping (all 256 threads): batch rb, dim octet rd0..rd0+7
  const int rb = tid >> 6;
  const int rd0 = (tid & 63) * 8;
  const int stidx = (rd0 >> 5) * 552 + ((rd0 >> 3) & 3) * 136 + rb * 8;  // u16 units
  bool slowmode = false;
  __syncthreads();

  for (int t = 0; t < T_; t++) {
    // ---- gates = h_{t-1} @ Whh : 2 N-tiles per wave (gate w), K=512 ----
    f32x4 a0 = {0.f, 0.f, 0.f, 0.f}, a1 = a0;
#pragma unroll
    for (int kk = 0; kk < 16; kk++) {
      bh8 af = *(const bh8*)(hstage + kk * 552 + aoff);
      a0 = __builtin_amdgcn_mfma_f32_16x16x32_bf16(af, bfr[0][kk], a0, 0, 0, 0);
      a1 = __builtin_amdgcn_mfma_f32_16x16x32_bf16(af, bfr[1][kk], a1, 0, 0, 0);
    }
    if (lc == 0) {                        // C rows 0-3 = batches
#pragma unroll
      for (int e = 0; e < 4; e++) {
        gl[e * 132 + w * 32 + lr] = a0[e];
        gl[e * 132 + w * 32 + 16 + lr] = a1[e];
      }
    }
    // B1: LDS-only drain barrier
    asm volatile("s_waitcnt lgkmcnt(0)\n\ts_barrier" ::: "memory");
    __builtin_amdgcn_sched_barrier(0);

    u16 hb = 0;
    if (tid < 128) {
      // ---- pointwise: one h-value per thread (batch pb, dim D0+pd) ----
      const float gi = gl[pb * 132 + pd]      + bf2f(xh[0]);
      const float gf = gl[pb * 132 + 32 + pd] + bf2f(xh[1]);
      const float gg = gl[pb * 132 + 64 + pd] + bf2f(xh[2]);
      const float go = gl[pb * 132 + 96 + pd] + bf2f(xh[3]);
      const float si = 1.f / (1.f + __expf(-gi));
      const float sf = 1.f / (1.f + __expf(-gf));
      const float tg = 1.f - 2.f / (__expf(2.f * gg) + 1.f);
      const float so = 1.f / (1.f + __expf(-go));
      ccv = sf * ccv + si * tg;
      const float hv = so * (1.f - 2.f / (__expf(2.f * ccv) + 1.f));
      hb = f2bf(hv);
      if (t + 1 < T_) {                   // fast publish, then shadow — both BEFORE any poll
        const u32 tagged = ((u32)(t + 1) << 16) | (u32)hb;
        const size_t idx = ((size_t)((t & 1) * 8 + grp) * 4 + pb) * 512 + gdim;
        asm volatile("global_store_dword %0, %1, off sc0"
                     :: "v"((u64)(uintptr_t)(fb + idx)), "v"(tagged) : "memory");
        (void)__hip_atomic_exchange(sb + idx, tagged, __ATOMIC_RELAXED,
                                    __HIP_MEMORY_SCOPE_AGENT);
      }
    }
    if (t + 1 < T_) {
      // ---- all threads: poll 2 contiguous dwordx4 (dims rd0..rd0+7, batch rb) ----
      const u32 tag = (u32)(t + 1);
      const size_t base = ((size_t)((t & 1) * 8 + grp) * 4 + rb) * 512 + rd0;
      const u64 pa = (u64)(uintptr_t)(fb + base);
      u32x4 qa, qb;
      if (!slowmode) {
        int rounds = 0;
        for (;;) {
          asm volatile("global_load_dwordx4 %0, %2, off sc0\n\t"
                       "global_load_dwordx4 %1, %2, off offset:16 sc0\n\t"
                       "s_waitcnt vmcnt(0)"
                       : "=&v"(qa), "=&v"(qb) : "v"(pa) : "memory");
          const bool bad = (qa[0] >> 16) != tag || (qa[1] >> 16) != tag ||
                           (qa[2] >> 16) != tag || (qa[3] >> 16) != tag ||
                           (qb[0] >> 16) != tag || (qb[1] >> 16) != tag ||
                           (qb[2] >> 16) != tag || (qb[3] >> 16) != tag;
          if (!__ballot(bad)) break;
          if (++rounds > 512) { slowmode = true; break; }
        }
      }
      if (slowmode) {                     // placement-independent fallback at LLC
        const u64* sp = (const u64*)(sb + base);
        for (;;) {
          u64 s0 = __hip_atomic_load(sp + 0, __ATOMIC_RELAXED, __HIP_MEMORY_SCOPE_AGENT);
          u64 s1 = __hip_atomic_load(sp + 1, __ATOMIC_RELAXED, __HIP_MEMORY_SCOPE_AGENT);
          u64 s2 = __hip_atomic_load(sp + 2, __ATOMIC_RELAXED, __HIP_MEMORY_SCOPE_AGENT);
          u64 s3 = __hip_atomic_load(sp + 3, __ATOMIC_RELAXED, __HIP_MEMORY_SCOPE_AGENT);
          qa[0] = (u32)s0; qa[1] = (u32)(s0 >> 32);
          qa[2] = (u32)s1; qa[3] = (u32)(s1 >> 32);
          qb[0] = (u32)s2; qb[1] = (u32)(s2 >> 32);
          qb[2] = (u32)s3; qb[3] = (u32)(s3 >> 32);
          const bool bad = (qa[0] >> 16) != tag || (qa[1] >> 16) != tag ||
                           (qa[2] >> 16) != tag || (qa[3] >> 16) != tag ||
                           (qb[0] >> 16) != tag || (qb[1] >> 16) != tag ||
                           (qb[2] >> 16) != tag || (qb[3] >> 16) != tag;
          if (!__ballot(bad)) break;
        }
      }
      // ---- stage as MFMA A-frag octet: one 16B LDS write ----
      u32x4 pw;
      pw[0] = (qa[0] & 0xffffu) | (qa[1] << 16);
      pw[1] = (qa[2] & 0xffffu) | (qa[3] << 16);
      pw[2] = (qb[0] & 0xffffu) | (qb[1] << 16);
      pw[3] = (qb[2] & 0xffffu) | (qb[3] << 16);
      *(u32x4*)(hstage + stidx) = pw;
    }
    if (tid < 128) {
      hs[((size_t)gbat * T_ + t) * 512 + gdim] = hb;
      if (t + 1 < T_) {                   // xg prefetch (fire-and-forget)
        const u16* xp = xg + ((size_t)(t + 1) * 32 + gbat) * NG + gdim;
#pragma unroll
        for (int g = 0; g < 4; g++) xh[g] = xp[g * 512];
      }
    }
    // B2: LDS-only drain barrier — hstage(t) ready; globals stay in flight
    asm volatile("s_waitcnt lgkmcnt(0)\n\ts_barrier" ::: "memory");
    __builtin_amdgcn_sched_barrier(0);
  }
}

extern "C" void kernel_launch(void* const* d_in, const int* in_sizes, int n_in,
                              void* d_out, int out_size, void* d_ws, size_t ws_size,
                              hipStream_t stream) {
  const int*   zi    = (const int*)d_in[0];
  const float* c     = (const float*)d_in[1];
  const float* emb   = (const float*)d_in[2];
  const float* W1    = (const float*)d_in[3];
  const float* b1    = (const float*)d_in[4];
  const float* W2    = (const float*)d_in[5];
  const float* b2    = (const float*)d_in[6];
  const float* W_ih  = (const float*)d_in[7];
  const float* b_ih  = (const float*)d_in[8];
  const float* W_hh  = (const float*)d_in[9];
  const float* b_hh  = (const float*)d_in[10];
  const float* W_out = (const float*)d_in[11];
  const float* b_out = (const float*)d_in[12];
  float* out = (float*)d_out;
  char* ws = (char*)d_ws;

  const size_t x_off   = 0;
  const size_t xg_off  = 65536000;
  const size_t pre_off = 32768000;
  const size_t w_off   = xg_off + 131072000;
  u16* xb    = (u16*)(ws + x_off);
  u16* hsb   = (u16*)(ws + x_off);
  u16* preb  = (u16*)(ws + pre_off);
  u16* xgb   = (u16*)(ws + xg_off);
  u16* h1b   = (u16*)(ws + xg_off);
  u16* W1t   = (u16*)(ws + w_off);           // [512][1024]
  u16* W2t   = W1t + 512 * 1024;             // [512][512]
  u16* Wiht  = W2t + 512 * 512;              // [2048][512]
  u16* Whht  = Wiht + 2048 * 512;            // [2048][512]
  u16* Woutt = Whht + 2048 * 512;            // [512][512]
  float* bsum = (float*)(Woutt + 512 * 512);
  u32* hbuf  = (u32*)(bsum + NG);            // fast 128KB + shadow 128KB

  hipMemsetAsync(hbuf, 0, 2 * 32768 * sizeof(u32), stream);

  wtrans_k<<<dim3(32, 16), 256, 0, stream>>>(W1, W1t, 1024, 512);
  wtrans_k<<<dim3(16, 16), 256, 0, stream>>>(W2, W2t, 512, 512);
  wtrans_k<<<dim3(16, 64), 256, 0, stream>>>(W_ih, Wiht, 512, 2048);
  wtrans_k<<<dim3(16, 64), 256, 0, stream>>>(W_hh, Whht, 512, 2048);
  wtrans_k<<<dim3(16, 16), 256, 0, stream>>>(W_out, Woutt, 512, 512);
  bsum_k<<<8, 256, 0, stream>>>(b_ih, b_hh, bsum);
  embed_k<<<8000, 256, 0, stream>>>(zi, emb, xb);
  ctrans_k<<<dim3(16, 16, 32), 256, 0, stream>>>(c, xb);

  gemm_k<true,  false><<<dim3(250, 4),  256, 0, stream>>>(xb,   W1t,   b1,    h1b,  32000, 512,  1024);
  gemm_k<false, false><<<dim3(250, 4),  256, 0, stream>>>(h1b,  W2t,   b2,    preb, 32000, 512,  512);
  gemm_k<false, false><<<dim3(250, 16), 256, 0, stream>>>(preb, Wiht,  bsum,  xgb,  32000, 2048, 512);
  scan_k<<<256, 256, 0, stream>>>(xgb, Whht, hsb, hbuf);
  gemm_k<false, true ><<<dim3(250, 4),  256, 0, stream>>>(hsb,  Woutt, b_out, out,  32000, 512,  512);
}